// Round 3
// baseline (1193.353 us; speedup 1.0000x reference)
//
#include <hip/hip_runtime.h>
#include <math.h>

// ---------------- CSR build (2 edge passes: rank+count, then place) ----------------

__global__ void rank_kernel(const int* __restrict__ ei, int* __restrict__ cnt,
                            int* __restrict__ rank, int E) {
  int e = blockIdx.x * blockDim.x + threadIdx.x;
  if (e < E) rank[e] = atomicAdd(&cnt[ei[E + e]], 1);
}

__global__ __launch_bounds__(1024) void scan_kernel(int* __restrict__ cnt,
                                                    int* __restrict__ offs, int N) {
  __shared__ int part[1024];
  int tid = threadIdx.x;
  int chunk = (N + 1023) >> 10;
  int s = tid * chunk;
  int epos = s + chunk; if (epos > N) epos = N;
  int sum = 0;
  for (int i = s; i < epos; ++i) sum += cnt[i];
  part[tid] = sum;
  __syncthreads();
  for (int off = 1; off < 1024; off <<= 1) {
    int v = (tid >= off) ? part[tid - off] : 0;
    __syncthreads();
    part[tid] += v;
    __syncthreads();
  }
  int base = part[tid] - sum;  // exclusive prefix of this thread's chunk
  for (int i = s; i < epos; ++i) {
    offs[i] = base;
    base += cnt[i];
  }
  if (tid == 1023) offs[N] = part[1023];
}

__global__ void place_kernel(const int* __restrict__ ei, const float* __restrict__ ea,
                             const int* __restrict__ offs, const int* __restrict__ rank,
                             int2* __restrict__ sedge, int E) {
  int e = blockIdx.x * blockDim.x + threadIdx.x;
  if (e >= E) return;
  int d = ei[E + e];
  sedge[offs[d] + rank[e]] = make_int2(ei[e], __float_as_int(ea[e]));
}

// ---------------- degree bucket-sort of nodes (wave load balance) ----------------

__global__ void dhist_kernel(const int* __restrict__ offs, int* __restrict__ dh, int N) {
  int n = blockIdx.x * blockDim.x + threadIdx.x;
  if (n >= N) return;
  int deg = offs[n + 1] - offs[n];
  int b = 255 - (deg < 255 ? deg : 255);  // descending degree order
  atomicAdd(&dh[b], 1);
}

__global__ __launch_bounds__(256) void dscan_kernel(const int* __restrict__ dh,
                                                    int* __restrict__ dcur) {
  __shared__ int part[256];
  int tid = threadIdx.x;
  int v = dh[tid];
  part[tid] = v;
  __syncthreads();
  for (int off = 1; off < 256; off <<= 1) {
    int u = (tid >= off) ? part[tid - off] : 0;
    __syncthreads();
    part[tid] += u;
    __syncthreads();
  }
  dcur[tid] = part[tid] - v;
}

__global__ void dscatter_kernel(const int* __restrict__ offs, int* __restrict__ dcur,
                                int* __restrict__ order, int N) {
  int n = blockIdx.x * blockDim.x + threadIdx.x;
  if (n >= N) return;
  int deg = offs[n + 1] - offs[n];
  int b = 255 - (deg < 255 ? deg : 255);
  int posn = atomicAdd(&dcur[b], 1);
  order[posn] = n;
}

// ---------------- P = h @ Wm1[:9] + bm1 (round 0 only; later rounds fused) -------

__global__ __launch_bounds__(64) void premsg_kernel(const float* __restrict__ h,
    const float* __restrict__ Wm1, const float* __restrict__ bm1,
    float* __restrict__ P, int N) {
  int n = blockIdx.x * 64 + threadIdx.x;
  if (n >= N) return;
  float hv[9];
  #pragma unroll
  for (int i = 0; i < 9; ++i) hv[i] = h[(size_t)n * 9 + i];
  float acc[32];
  #pragma unroll
  for (int k = 0; k < 32; ++k) acc[k] = bm1[k];
  #pragma unroll
  for (int i = 0; i < 9; ++i)
    #pragma unroll
    for (int k = 0; k < 32; ++k) acc[k] = fmaf(hv[i], Wm1[i * 32 + k], acc[k]);
  float4* Pv = (float4*)(P + (size_t)n * 32);
  #pragma unroll
  for (int jv = 0; jv < 8; ++jv)
    Pv[jv] = make_float4(acc[jv * 4], acc[jv * 4 + 1], acc[jv * 4 + 2], acc[jv * 4 + 3]);
}

// ---------------- fused aggregate + update (+P-next or +h2o head) ----------------
// 8 lanes per node (TLP hides gather + scalar-weight-load latency; no software
// prefetch — the round-1 pipeline's np[]/copy chain defeated register promotion
// and thrashed scratch: 72 GB FETCH, VGPR=80). Live set now ~90 floats.

template <int MODE>  // 0: write hout + Pout ; 1: final round, write sigmoid head to out
__global__ __launch_bounds__(64, 2) void agg_update_kernel(
    const int* __restrict__ offs, const int2* __restrict__ sedge,
    const int* __restrict__ order,
    const float* __restrict__ Pin, const float* __restrict__ hin,
    float* __restrict__ hout, float* __restrict__ Pout,
    const float* __restrict__ Wm1, const float* __restrict__ bm1,
    const float* __restrict__ Wm2, const float* __restrict__ bm2,
    const float* __restrict__ Wu1, const float* __restrict__ bu1,
    const float* __restrict__ Wu2, const float* __restrict__ bu2,
    const float* __restrict__ Wh1, const float* __restrict__ bh1,
    const float* __restrict__ Wh2, const float* __restrict__ bh2,
    float* __restrict__ out, int N) {
  int gid = blockIdx.x * 64 + threadIdx.x;
  if (gid >= 8 * N) return;
  int n = order[gid >> 3];
  int sub = threadIdx.x & 7;
  int e1 = offs[n + 1];
  const float* __restrict__ Wm1t = Wm1 + 288;  // row 9 (edge_attr row)
  float aggr[32];
  #pragma unroll
  for (int k = 0; k < 32; ++k) aggr[k] = 0.f;

  for (int e = offs[n] + sub; e < e1; e += 8) {
    int2 se = sedge[e];
    float eav = __int_as_float(se.y);
    const float4* Pv = (const float4*)(Pin + (size_t)se.x * 32);
    float p[32];
    #pragma unroll
    for (int jv = 0; jv < 8; ++jv) {
      float4 v = Pv[jv];
      p[jv*4+0] = v.x; p[jv*4+1] = v.y; p[jv*4+2] = v.z; p[jv*4+3] = v.w;
    }
    // layer-1 tail in place: p becomes h1 = relu(P[src] + ea * Wm1[row 9])
    #pragma unroll
    for (int j = 0; j < 32; ++j) p[j] = fmaxf(fmaf(eav, Wm1t[j], p[j]), 0.f);
    // layer-2 in 4 chunks of 8 output channels (weights wave-uniform -> s_loads)
    #pragma unroll
    for (int c = 0; c < 4; ++c) {
      float t[8];
      #pragma unroll
      for (int k = 0; k < 8; ++k) t[k] = bm2[c * 8 + k];
      #pragma unroll
      for (int j = 0; j < 32; ++j) {
        float hj = p[j];
        #pragma unroll
        for (int k = 0; k < 8; ++k) t[k] = fmaf(hj, Wm2[j * 32 + c * 8 + k], t[k]);
      }
      #pragma unroll
      for (int k = 0; k < 8; ++k) aggr[c * 8 + k] += fmaxf(t[k], 0.f);
    }
  }
  // combine the 8 sub-lanes of this node
  #pragma unroll
  for (int k = 0; k < 32; ++k) {
    aggr[k] += __shfl_xor(aggr[k], 1);
    aggr[k] += __shfl_xor(aggr[k], 2);
    aggr[k] += __shfl_xor(aggr[k], 4);
  }
  // update MLP: u1 = relu([h; aggr] @ Wu1 + bu1); emb = relu(u1 @ Wu2 + bu2)
  float hv[9];
  #pragma unroll
  for (int i = 0; i < 9; ++i) hv[i] = hin[(size_t)n * 9 + i];
  float u1[16];
  #pragma unroll
  for (int q = 0; q < 16; ++q) {
    float a = bu1[q];
    #pragma unroll
    for (int i = 0; i < 9; ++i) a = fmaf(hv[i], Wu1[i * 16 + q], a);
    #pragma unroll
    for (int k = 0; k < 32; ++k) a = fmaf(aggr[k], Wu1[(9 + k) * 16 + q], a);
    u1[q] = fmaxf(a, 0.f);
  }
  float emb[8];
  #pragma unroll
  for (int r = 0; r < 8; ++r) {
    float a = bu2[r];
    #pragma unroll
    for (int q = 0; q < 16; ++q) a = fmaf(u1[q], Wu2[q * 8 + r], a);
    emb[r] = fmaxf(a, 0.f);
  }
  if constexpr (MODE == 0) {
    // fused premessage for next round: P' = h' @ Wm1[:9] + bm1, h' = [state, emb]
    float acc[32];
    #pragma unroll
    for (int k = 0; k < 32; ++k) acc[k] = fmaf(hv[0], Wm1[k], bm1[k]);
    #pragma unroll
    for (int r = 0; r < 8; ++r)
      #pragma unroll
      for (int k = 0; k < 32; ++k) acc[k] = fmaf(emb[r], Wm1[(1 + r) * 32 + k], acc[k]);
    if (sub == 0) {
      hout[(size_t)n * 9] = hv[0];
      #pragma unroll
      for (int r = 0; r < 8; ++r) hout[(size_t)n * 9 + 1 + r] = emb[r];
      float4* Pv = (float4*)(Pout + (size_t)n * 32);
      #pragma unroll
      for (int jv = 0; jv < 8; ++jv)
        Pv[jv] = make_float4(acc[jv*4], acc[jv*4+1], acc[jv*4+2], acc[jv*4+3]);
    }
  } else {
    // h2o head: out = sigmoid(relu(emb @ Wh1 + bh1) @ Wh2 + bh2)
    float o[16];
    #pragma unroll
    for (int q = 0; q < 16; ++q) {
      float a = bh1[q];
      #pragma unroll
      for (int r = 0; r < 8; ++r) a = fmaf(emb[r], Wh1[r * 16 + q], a);
      o[q] = fmaxf(a, 0.f);
    }
    float z = bh2[0];
    #pragma unroll
    for (int q = 0; q < 16; ++q) z = fmaf(o[q], Wh2[q], z);
    if (sub == 0) out[n] = 1.f / (1.f + expf(-z));
  }
}

// ---------------- launch ----------------

extern "C" void kernel_launch(void* const* d_in, const int* in_sizes, int n_in,
                              void* d_out, int out_size, void* d_ws, size_t ws_size,
                              hipStream_t stream) {
  const float* x   = (const float*)d_in[0];
  const int*   ei  = (const int*)d_in[1];
  const float* ea  = (const float*)d_in[2];
  const float* Wm1 = (const float*)d_in[3];
  const float* bm1 = (const float*)d_in[4];
  const float* Wm2 = (const float*)d_in[5];
  const float* bm2 = (const float*)d_in[6];
  const float* Wu1 = (const float*)d_in[7];
  const float* bu1 = (const float*)d_in[8];
  const float* Wu2 = (const float*)d_in[9];
  const float* bu2 = (const float*)d_in[10];
  const float* Wh1 = (const float*)d_in[11];
  const float* bh1 = (const float*)d_in[12];
  const float* Wh2 = (const float*)d_in[13];
  const float* bh2 = (const float*)d_in[14];
  float* out = (float*)d_out;
  const int N = in_sizes[0] / 9;
  const int E = in_sizes[2];

  char* wsb = (char*)d_ws;
  size_t pos = 0;
  auto alloc = [&](size_t b) {
    pos = (pos + 255) & ~(size_t)255;
    char* p = wsb + pos;
    pos += b;
    return (void*)p;
  };
  int*   cnt   = (int*)alloc((size_t)N * 4);        // histogram
  int*   offs  = (int*)alloc((size_t)(N + 1) * 4);  // CSR offsets
  int2*  sedge = (int2*)alloc((size_t)E * 8);       // (src, edge_attr bits), dst-sorted
  int*   dh    = (int*)alloc(256 * 4);
  int*   dcur  = (int*)alloc(256 * 4);
  int*   order = (int*)alloc((size_t)N * 4);        // degree-sorted node order
  float* P0    = (float*)alloc((size_t)N * 32 * 4);
  float* P1    = (float*)alloc((size_t)N * 32 * 4);
  float* hA    = (float*)alloc((size_t)N * 9 * 4);
  float* hB    = (float*)alloc((size_t)N * 9 * 4);
  int*   rank  = (int*)P1;  // alias: rank[E] dead before P1's first write (agg round 0)

  hipMemsetAsync(cnt, 0, (size_t)N * 4, stream);
  hipMemsetAsync(dh, 0, 256 * 4, stream);

  premsg_kernel<<<(N + 63) / 64, 64, 0, stream>>>(x, Wm1, bm1, P0, N);
  rank_kernel<<<(E + 255) / 256, 256, 0, stream>>>(ei, cnt, rank, E);
  scan_kernel<<<1, 1024, 0, stream>>>(cnt, offs, N);
  place_kernel<<<(E + 255) / 256, 256, 0, stream>>>(ei, ea, offs, rank, sedge, E);
  dhist_kernel<<<(N + 255) / 256, 256, 0, stream>>>(offs, dh, N);
  dscan_kernel<<<1, 256, 0, stream>>>(dh, dcur);
  dscatter_kernel<<<(N + 255) / 256, 256, 0, stream>>>(offs, dcur, order, N);

  int gb = (8 * N + 63) / 64;
  agg_update_kernel<0><<<gb, 64, 0, stream>>>(offs, sedge, order, P0, x, hA, P1,
      Wm1, bm1, Wm2, bm2, Wu1, bu1, Wu2, bu2, Wh1, bh1, Wh2, bh2, nullptr, N);
  agg_update_kernel<0><<<gb, 64, 0, stream>>>(offs, sedge, order, P1, hA, hB, P0,
      Wm1, bm1, Wm2, bm2, Wu1, bu1, Wu2, bu2, Wh1, bh1, Wh2, bh2, nullptr, N);
  agg_update_kernel<1><<<gb, 64, 0, stream>>>(offs, sedge, order, P0, hB, nullptr, nullptr,
      Wm1, bm1, Wm2, bm2, Wu1, bu1, Wu2, bu2, Wh1, bh1, Wh2, bh2, out, N);
}

// Round 4
// 908.707 us; speedup vs baseline: 1.3132x; 1.3132x over previous
//
#include <hip/hip_runtime.h>
#include <math.h>

// ---------------- CSR build (2 edge passes: rank+count, then place) ----------------

__global__ void rank_kernel(const int* __restrict__ ei, int* __restrict__ cnt,
                            int* __restrict__ rank, int E) {
  int e = blockIdx.x * blockDim.x + threadIdx.x;
  if (e < E) rank[e] = atomicAdd(&cnt[ei[E + e]], 1);
}

__global__ __launch_bounds__(1024) void scan_kernel(int* __restrict__ cnt,
                                                    int* __restrict__ offs, int N) {
  __shared__ int part[1024];
  int tid = threadIdx.x;
  int chunk = (N + 1023) >> 10;
  int s = tid * chunk;
  int epos = s + chunk; if (epos > N) epos = N;
  int sum = 0;
  for (int i = s; i < epos; ++i) sum += cnt[i];
  part[tid] = sum;
  __syncthreads();
  for (int off = 1; off < 1024; off <<= 1) {
    int v = (tid >= off) ? part[tid - off] : 0;
    __syncthreads();
    part[tid] += v;
    __syncthreads();
  }
  int base = part[tid] - sum;  // exclusive prefix of this thread's chunk
  for (int i = s; i < epos; ++i) {
    offs[i] = base;
    base += cnt[i];
  }
  if (tid == 1023) offs[N] = part[1023];
}

__global__ void place_kernel(const int* __restrict__ ei, const float* __restrict__ ea,
                             const int* __restrict__ offs, const int* __restrict__ rank,
                             int2* __restrict__ sedge, int E) {
  int e = blockIdx.x * blockDim.x + threadIdx.x;
  if (e >= E) return;
  int d = ei[E + e];
  sedge[offs[d] + rank[e]] = make_int2(ei[e], __float_as_int(ea[e]));
}

// ---------------- degree bucket-sort of nodes (wave load balance) ----------------

__global__ void dhist_kernel(const int* __restrict__ offs, int* __restrict__ dh, int N) {
  int n = blockIdx.x * blockDim.x + threadIdx.x;
  if (n >= N) return;
  int deg = offs[n + 1] - offs[n];
  int b = 255 - (deg < 255 ? deg : 255);  // descending degree order
  atomicAdd(&dh[b], 1);
}

__global__ __launch_bounds__(256) void dscan_kernel(const int* __restrict__ dh,
                                                    int* __restrict__ dcur) {
  __shared__ int part[256];
  int tid = threadIdx.x;
  int v = dh[tid];
  part[tid] = v;
  __syncthreads();
  for (int off = 1; off < 256; off <<= 1) {
    int u = (tid >= off) ? part[tid - off] : 0;
    __syncthreads();
    part[tid] += u;
    __syncthreads();
  }
  dcur[tid] = part[tid] - v;
}

__global__ void dscatter_kernel(const int* __restrict__ offs, int* __restrict__ dcur,
                                int* __restrict__ order, int N) {
  int n = blockIdx.x * blockDim.x + threadIdx.x;
  if (n >= N) return;
  int deg = offs[n + 1] - offs[n];
  int b = 255 - (deg < 255 ? deg : 255);
  int posn = atomicAdd(&dcur[b], 1);
  order[posn] = n;
}

// ---------------- P = h @ Wm1[:9] + bm1 (round 0 only; later rounds fused) -------

__global__ __launch_bounds__(256) void premsg_kernel(const float* __restrict__ h,
    const float* __restrict__ Wm1, const float* __restrict__ bm1,
    float* __restrict__ P, int N) {
  int n = blockIdx.x * blockDim.x + threadIdx.x;
  if (n >= N) return;
  float hv[9];
  #pragma unroll
  for (int i = 0; i < 9; ++i) hv[i] = h[(size_t)n * 9 + i];
  float acc[32];
  #pragma unroll
  for (int k = 0; k < 32; ++k) acc[k] = bm1[k];
  #pragma unroll
  for (int i = 0; i < 9; ++i)
    #pragma unroll
    for (int k = 0; k < 32; ++k) acc[k] = fmaf(hv[i], Wm1[i * 32 + k], acc[k]);
  float4* Pv = (float4*)(P + (size_t)n * 32);
  #pragma unroll
  for (int jv = 0; jv < 8; ++jv)
    Pv[jv] = make_float4(acc[jv * 4], acc[jv * 4 + 1], acc[jv * 4 + 2], acc[jv * 4 + 3]);
}

// ---------------- edge aggregate ONLY (tail split off => live set ~80 floats) ----
// 8 lanes per node, edges strided by 8, shfl_xor combine, write aggr to global.

__global__ __launch_bounds__(256) void agg_kernel(
    const int* __restrict__ offs, const int2* __restrict__ sedge,
    const int* __restrict__ order,
    const float* __restrict__ Pin, float* __restrict__ G,
    const float* __restrict__ Wm1, const float* __restrict__ Wm2,
    const float* __restrict__ bm2, int N) {
  int gid = blockIdx.x * blockDim.x + threadIdx.x;
  if (gid >= 8 * N) return;
  int n = order[gid >> 3];
  int sub = threadIdx.x & 7;
  int e1 = offs[n + 1];
  const float* __restrict__ Wm1t = Wm1 + 288;  // row 9 (edge_attr row)
  float aggr[32];
  #pragma unroll
  for (int k = 0; k < 32; ++k) aggr[k] = 0.f;

  for (int e = offs[n] + sub; e < e1; e += 8) {
    int2 se = sedge[e];
    float eav = __int_as_float(se.y);
    const float4* Pv = (const float4*)(Pin + (size_t)se.x * 32);
    float p[32];
    #pragma unroll
    for (int jv = 0; jv < 8; ++jv) {
      float4 v = Pv[jv];
      p[jv*4+0] = v.x; p[jv*4+1] = v.y; p[jv*4+2] = v.z; p[jv*4+3] = v.w;
    }
    // layer-1 tail in place: p becomes h1 = relu(P[src] + ea * Wm1[row 9])
    #pragma unroll
    for (int j = 0; j < 32; ++j) p[j] = fmaxf(fmaf(eav, Wm1t[j], p[j]), 0.f);
    // layer-2 in 4 chunks of 8 output channels (weights wave-uniform -> s_loads)
    #pragma unroll
    for (int c = 0; c < 4; ++c) {
      float t[8];
      #pragma unroll
      for (int k = 0; k < 8; ++k) t[k] = bm2[c * 8 + k];
      #pragma unroll
      for (int j = 0; j < 32; ++j) {
        float hj = p[j];
        #pragma unroll
        for (int k = 0; k < 8; ++k) t[k] = fmaf(hj, Wm2[j * 32 + c * 8 + k], t[k]);
      }
      #pragma unroll
      for (int k = 0; k < 8; ++k) aggr[c * 8 + k] += fmaxf(t[k], 0.f);
    }
  }
  // combine the 8 sub-lanes of this node
  #pragma unroll
  for (int k = 0; k < 32; ++k) {
    aggr[k] += __shfl_xor(aggr[k], 1);
    aggr[k] += __shfl_xor(aggr[k], 2);
    aggr[k] += __shfl_xor(aggr[k], 4);
  }
  if (sub == 0) {
    float4* Gv = (float4*)(G + (size_t)n * 32);
    #pragma unroll
    for (int jv = 0; jv < 8; ++jv)
      Gv[jv] = make_float4(aggr[jv*4], aggr[jv*4+1], aggr[jv*4+2], aggr[jv*4+3]);
  }
}

// ---------------- node update (+ premsg for next round, or h2o head) -------------

template <int MODE>  // 0: write hout + Pout ; 1: final round, write sigmoid head
__global__ __launch_bounds__(256) void update_kernel(
    const float* __restrict__ G, const float* __restrict__ hin,
    float* __restrict__ hout, float* __restrict__ Pout,
    const float* __restrict__ Wm1, const float* __restrict__ bm1,
    const float* __restrict__ Wu1, const float* __restrict__ bu1,
    const float* __restrict__ Wu2, const float* __restrict__ bu2,
    const float* __restrict__ Wh1, const float* __restrict__ bh1,
    const float* __restrict__ Wh2, const float* __restrict__ bh2,
    float* __restrict__ out, int N) {
  int n = blockIdx.x * blockDim.x + threadIdx.x;
  if (n >= N) return;
  float aggr[32];
  const float4* Gv = (const float4*)(G + (size_t)n * 32);
  #pragma unroll
  for (int jv = 0; jv < 8; ++jv) {
    float4 v = Gv[jv];
    aggr[jv*4+0] = v.x; aggr[jv*4+1] = v.y; aggr[jv*4+2] = v.z; aggr[jv*4+3] = v.w;
  }
  float hv[9];
  #pragma unroll
  for (int i = 0; i < 9; ++i) hv[i] = hin[(size_t)n * 9 + i];
  float u1[16];
  #pragma unroll
  for (int q = 0; q < 16; ++q) {
    float a = bu1[q];
    #pragma unroll
    for (int i = 0; i < 9; ++i) a = fmaf(hv[i], Wu1[i * 16 + q], a);
    #pragma unroll
    for (int k = 0; k < 32; ++k) a = fmaf(aggr[k], Wu1[(9 + k) * 16 + q], a);
    u1[q] = fmaxf(a, 0.f);
  }
  float emb[8];
  #pragma unroll
  for (int r = 0; r < 8; ++r) {
    float a = bu2[r];
    #pragma unroll
    for (int q = 0; q < 16; ++q) a = fmaf(u1[q], Wu2[q * 8 + r], a);
    emb[r] = fmaxf(a, 0.f);
  }
  if constexpr (MODE == 0) {
    // fused premessage for next round: P' = h' @ Wm1[:9] + bm1, h' = [state, emb]
    float acc[32];
    #pragma unroll
    for (int k = 0; k < 32; ++k) acc[k] = fmaf(hv[0], Wm1[k], bm1[k]);
    #pragma unroll
    for (int r = 0; r < 8; ++r)
      #pragma unroll
      for (int k = 0; k < 32; ++k) acc[k] = fmaf(emb[r], Wm1[(1 + r) * 32 + k], acc[k]);
    hout[(size_t)n * 9] = hv[0];
    #pragma unroll
    for (int r = 0; r < 8; ++r) hout[(size_t)n * 9 + 1 + r] = emb[r];
    float4* Pv = (float4*)(Pout + (size_t)n * 32);
    #pragma unroll
    for (int jv = 0; jv < 8; ++jv)
      Pv[jv] = make_float4(acc[jv*4], acc[jv*4+1], acc[jv*4+2], acc[jv*4+3]);
  } else {
    // h2o head: out = sigmoid(relu(emb @ Wh1 + bh1) @ Wh2 + bh2)
    float o[16];
    #pragma unroll
    for (int q = 0; q < 16; ++q) {
      float a = bh1[q];
      #pragma unroll
      for (int r = 0; r < 8; ++r) a = fmaf(emb[r], Wh1[r * 16 + q], a);
      o[q] = fmaxf(a, 0.f);
    }
    float z = bh2[0];
    #pragma unroll
    for (int q = 0; q < 16; ++q) z = fmaf(o[q], Wh2[q], z);
    out[n] = 1.f / (1.f + expf(-z));
  }
}

// ---------------- launch ----------------

extern "C" void kernel_launch(void* const* d_in, const int* in_sizes, int n_in,
                              void* d_out, int out_size, void* d_ws, size_t ws_size,
                              hipStream_t stream) {
  const float* x   = (const float*)d_in[0];
  const int*   ei  = (const int*)d_in[1];
  const float* ea  = (const float*)d_in[2];
  const float* Wm1 = (const float*)d_in[3];
  const float* bm1 = (const float*)d_in[4];
  const float* Wm2 = (const float*)d_in[5];
  const float* bm2 = (const float*)d_in[6];
  const float* Wu1 = (const float*)d_in[7];
  const float* bu1 = (const float*)d_in[8];
  const float* Wu2 = (const float*)d_in[9];
  const float* bu2 = (const float*)d_in[10];
  const float* Wh1 = (const float*)d_in[11];
  const float* bh1 = (const float*)d_in[12];
  const float* Wh2 = (const float*)d_in[13];
  const float* bh2 = (const float*)d_in[14];
  float* out = (float*)d_out;
  const int N = in_sizes[0] / 9;
  const int E = in_sizes[2];

  char* wsb = (char*)d_ws;
  size_t pos = 0;
  auto alloc = [&](size_t b) {
    pos = (pos + 255) & ~(size_t)255;
    char* p = wsb + pos;
    pos += b;
    return (void*)p;
  };
  int*   cnt   = (int*)alloc((size_t)N * 4);        // histogram
  int*   offs  = (int*)alloc((size_t)(N + 1) * 4);  // CSR offsets
  int2*  sedge = (int2*)alloc((size_t)E * 8);       // (src, edge_attr bits), dst-sorted
  int*   dh    = (int*)alloc(256 * 4);
  int*   dcur  = (int*)alloc(256 * 4);
  int*   order = (int*)alloc((size_t)N * 4);        // degree-sorted node order
  float* P0    = (float*)alloc((size_t)N * 32 * 4);
  float* P1    = (float*)alloc((size_t)N * 32 * 4);
  float* G     = (float*)alloc((size_t)N * 32 * 4); // per-node aggregate
  float* hA    = (float*)alloc((size_t)N * 9 * 4);
  float* hB    = (float*)alloc((size_t)N * 9 * 4);
  int*   rank  = (int*)P1;  // alias: rank[E] dead before P1's first write

  hipMemsetAsync(cnt, 0, (size_t)N * 4, stream);
  hipMemsetAsync(dh, 0, 256 * 4, stream);

  premsg_kernel<<<(N + 255) / 256, 256, 0, stream>>>(x, Wm1, bm1, P0, N);
  rank_kernel<<<(E + 255) / 256, 256, 0, stream>>>(ei, cnt, rank, E);
  scan_kernel<<<1, 1024, 0, stream>>>(cnt, offs, N);
  place_kernel<<<(E + 255) / 256, 256, 0, stream>>>(ei, ea, offs, rank, sedge, E);
  dhist_kernel<<<(N + 255) / 256, 256, 0, stream>>>(offs, dh, N);
  dscan_kernel<<<1, 256, 0, stream>>>(dh, dcur);
  dscatter_kernel<<<(N + 255) / 256, 256, 0, stream>>>(offs, dcur, order, N);

  int ab = (8 * N + 255) / 256;
  int ub = (N + 255) / 256;
  // round 0
  agg_kernel<<<ab, 256, 0, stream>>>(offs, sedge, order, P0, G, Wm1, Wm2, bm2, N);
  update_kernel<0><<<ub, 256, 0, stream>>>(G, x, hA, P1,
      Wm1, bm1, Wu1, bu1, Wu2, bu2, Wh1, bh1, Wh2, bh2, nullptr, N);
  // round 1
  agg_kernel<<<ab, 256, 0, stream>>>(offs, sedge, order, P1, G, Wm1, Wm2, bm2, N);
  update_kernel<0><<<ub, 256, 0, stream>>>(G, hA, hB, P0,
      Wm1, bm1, Wu1, bu1, Wu2, bu2, Wh1, bh1, Wh2, bh2, nullptr, N);
  // round 2 + head
  agg_kernel<<<ab, 256, 0, stream>>>(offs, sedge, order, P0, G, Wm1, Wm2, bm2, N);
  update_kernel<1><<<ub, 256, 0, stream>>>(G, hB, nullptr, nullptr,
      Wm1, bm1, Wu1, bu1, Wu2, bu2, Wh1, bh1, Wh2, bh2, out, N);
}

// Round 5
// 759.748 us; speedup vs baseline: 1.5707x; 1.1961x over previous
//
#include <hip/hip_runtime.h>
#include <math.h>

// ---------------- CSR build (2 edge passes: rank+count, then place) ----------------

__global__ void rank_kernel(const int* __restrict__ ei, int* __restrict__ cnt,
                            int* __restrict__ rank, int E) {
  int e = blockIdx.x * blockDim.x + threadIdx.x;
  if (e < E) rank[e] = atomicAdd(&cnt[ei[E + e]], 1);
}

__global__ __launch_bounds__(1024) void scan_kernel(int* __restrict__ cnt,
                                                    int* __restrict__ offs, int N) {
  __shared__ int part[1024];
  int tid = threadIdx.x;
  int chunk = (N + 1023) >> 10;
  int s = tid * chunk;
  int epos = s + chunk; if (epos > N) epos = N;
  int sum = 0;
  for (int i = s; i < epos; ++i) sum += cnt[i];
  part[tid] = sum;
  __syncthreads();
  for (int off = 1; off < 1024; off <<= 1) {
    int v = (tid >= off) ? part[tid - off] : 0;
    __syncthreads();
    part[tid] += v;
    __syncthreads();
  }
  int base = part[tid] - sum;  // exclusive prefix of this thread's chunk
  for (int i = s; i < epos; ++i) {
    offs[i] = base;
    base += cnt[i];
  }
  if (tid == 1023) offs[N] = part[1023];
}

// sedge[i] = (src, dst, edge_attr bits, 0), sorted by dst
__global__ void place_kernel(const int* __restrict__ ei, const float* __restrict__ ea,
                             const int* __restrict__ offs, const int* __restrict__ rank,
                             int4* __restrict__ sedge, int E) {
  int e = blockIdx.x * blockDim.x + threadIdx.x;
  if (e >= E) return;
  int d = ei[E + e];
  sedge[offs[d] + rank[e]] = make_int4(ei[e], d, __float_as_int(ea[e]), 0);
}

// ---------------- P = h @ Wm1[:9] + bm1 (round 0 only; later rounds fused) -------

__global__ __launch_bounds__(256) void premsg_kernel(const float* __restrict__ h,
    const float* __restrict__ Wm1, const float* __restrict__ bm1,
    float* __restrict__ P, int N) {
  int n = blockIdx.x * blockDim.x + threadIdx.x;
  if (n >= N) return;
  float hv[9];
  #pragma unroll
  for (int i = 0; i < 9; ++i) hv[i] = h[(size_t)n * 9 + i];
  float acc[32];
  #pragma unroll
  for (int k = 0; k < 32; ++k) acc[k] = bm1[k];
  #pragma unroll
  for (int i = 0; i < 9; ++i)
    #pragma unroll
    for (int k = 0; k < 32; ++k) acc[k] = fmaf(hv[i], Wm1[i * 32 + k], acc[k]);
  float4* Pv = (float4*)(P + (size_t)n * 32);
  #pragma unroll
  for (int jv = 0; jv < 8; ++jv)
    Pv[jv] = make_float4(acc[jv * 4], acc[jv * 4 + 1], acc[jv * 4 + 2], acc[jv * 4 + 3]);
}

// ---------------- edge-parallel message + segmented-scan aggregate ----------------
// One lane per edge (perfect load balance, ~64 VGPR -> 8 waves/SIMD). Edges are
// dst-sorted, so within each 64-lane window the per-dst reduction is a
// conditional Hillis-Steele scan (exact for sorted keys); only run-end lanes
// (~3/window) atomicAdd to G. ~2.4M float atomics/round vs 51M naive.

__global__ __launch_bounds__(256) void agg_kernel(
    const int4* __restrict__ sedge, const float* __restrict__ Pin,
    float* __restrict__ G, const float* __restrict__ Wm1,
    const float* __restrict__ Wm2, const float* __restrict__ bm2, int E) {
  int e = blockIdx.x * blockDim.x + threadIdx.x;
  int lane = threadIdx.x & 63;
  bool valid = e < E;
  int4 se = valid ? sedge[e] : make_int4(0, -1, 0, 0);
  int dst = se.y;
  float eav = __int_as_float(se.z);
  const float* __restrict__ Wm1t = Wm1 + 288;  // row 9 (edge_attr row)

  float p[32];
  const float4* Pv = (const float4*)(Pin + (size_t)se.x * 32);
  #pragma unroll
  for (int jv = 0; jv < 8; ++jv) {
    float4 v = Pv[jv];
    p[jv*4+0] = v.x; p[jv*4+1] = v.y; p[jv*4+2] = v.z; p[jv*4+3] = v.w;
  }
  // layer-1 tail in place: p becomes h1 = relu(P[src] + ea * Wm1[row 9])
  #pragma unroll
  for (int j = 0; j < 32; ++j) p[j] = fmaxf(fmaf(eav, Wm1t[j], p[j]), 0.f);

  int nextdst = __shfl_down(dst, 1);
  bool is_end = valid && ((lane == 63) || (nextdst != dst));

  // layer-2 in 4 chunks of 8 channels; scan+atomic per chunk keeps live set small
  #pragma unroll
  for (int c = 0; c < 4; ++c) {
    float t[8];
    #pragma unroll
    for (int k = 0; k < 8; ++k) t[k] = bm2[c * 8 + k];
    #pragma unroll
    for (int j = 0; j < 32; ++j) {
      float hj = p[j];
      #pragma unroll
      for (int k = 0; k < 8; ++k) t[k] = fmaf(hj, Wm2[j * 32 + c * 8 + k], t[k]);
    }
    #pragma unroll
    for (int k = 0; k < 8; ++k) t[k] = fmaxf(t[k], 0.f);
    // segmented inclusive scan by dst across the wave (dst sorted; invalid
    // lanes have dst=-1 and form their own segment, never polluting real ones)
    #pragma unroll
    for (int s = 1; s < 64; s <<= 1) {
      int pd = __shfl_up(dst, s);
      bool match = (lane >= s) && (pd == dst);
      #pragma unroll
      for (int k = 0; k < 8; ++k) {
        float u = __shfl_up(t[k], s);
        t[k] += match ? u : 0.f;
      }
    }
    if (is_end) {
      float* g = G + (size_t)dst * 32 + c * 8;
      #pragma unroll
      for (int k = 0; k < 8; ++k) atomicAdd(&g[k], t[k]);
    }
  }
}

// ---------------- node update (+ premsg for next round, or h2o head) -------------

template <int MODE>  // 0: write hout + Pout ; 1: final round, write sigmoid head
__global__ __launch_bounds__(256) void update_kernel(
    const float* __restrict__ G, const float* __restrict__ hin,
    float* __restrict__ hout, float* __restrict__ Pout,
    const float* __restrict__ Wm1, const float* __restrict__ bm1,
    const float* __restrict__ Wu1, const float* __restrict__ bu1,
    const float* __restrict__ Wu2, const float* __restrict__ bu2,
    const float* __restrict__ Wh1, const float* __restrict__ bh1,
    const float* __restrict__ Wh2, const float* __restrict__ bh2,
    float* __restrict__ out, int N) {
  int n = blockIdx.x * blockDim.x + threadIdx.x;
  if (n >= N) return;
  float aggr[32];
  const float4* Gv = (const float4*)(G + (size_t)n * 32);
  #pragma unroll
  for (int jv = 0; jv < 8; ++jv) {
    float4 v = Gv[jv];
    aggr[jv*4+0] = v.x; aggr[jv*4+1] = v.y; aggr[jv*4+2] = v.z; aggr[jv*4+3] = v.w;
  }
  float hv[9];
  #pragma unroll
  for (int i = 0; i < 9; ++i) hv[i] = hin[(size_t)n * 9 + i];
  float u1[16];
  #pragma unroll
  for (int q = 0; q < 16; ++q) {
    float a = bu1[q];
    #pragma unroll
    for (int i = 0; i < 9; ++i) a = fmaf(hv[i], Wu1[i * 16 + q], a);
    #pragma unroll
    for (int k = 0; k < 32; ++k) a = fmaf(aggr[k], Wu1[(9 + k) * 16 + q], a);
    u1[q] = fmaxf(a, 0.f);
  }
  float emb[8];
  #pragma unroll
  for (int r = 0; r < 8; ++r) {
    float a = bu2[r];
    #pragma unroll
    for (int q = 0; q < 16; ++q) a = fmaf(u1[q], Wu2[q * 8 + r], a);
    emb[r] = fmaxf(a, 0.f);
  }
  if constexpr (MODE == 0) {
    // fused premessage for next round: P' = h' @ Wm1[:9] + bm1, h' = [state, emb]
    float acc[32];
    #pragma unroll
    for (int k = 0; k < 32; ++k) acc[k] = fmaf(hv[0], Wm1[k], bm1[k]);
    #pragma unroll
    for (int r = 0; r < 8; ++r)
      #pragma unroll
      for (int k = 0; k < 32; ++k) acc[k] = fmaf(emb[r], Wm1[(1 + r) * 32 + k], acc[k]);
    hout[(size_t)n * 9] = hv[0];
    #pragma unroll
    for (int r = 0; r < 8; ++r) hout[(size_t)n * 9 + 1 + r] = emb[r];
    float4* Pv = (float4*)(Pout + (size_t)n * 32);
    #pragma unroll
    for (int jv = 0; jv < 8; ++jv)
      Pv[jv] = make_float4(acc[jv*4], acc[jv*4+1], acc[jv*4+2], acc[jv*4+3]);
  } else {
    // h2o head: out = sigmoid(relu(emb @ Wh1 + bh1) @ Wh2 + bh2)
    float o[16];
    #pragma unroll
    for (int q = 0; q < 16; ++q) {
      float a = bh1[q];
      #pragma unroll
      for (int r = 0; r < 8; ++r) a = fmaf(emb[r], Wh1[r * 16 + q], a);
      o[q] = fmaxf(a, 0.f);
    }
    float z = bh2[0];
    #pragma unroll
    for (int q = 0; q < 16; ++q) z = fmaf(o[q], Wh2[q], z);
    out[n] = 1.f / (1.f + expf(-z));
  }
}

// ---------------- launch ----------------

extern "C" void kernel_launch(void* const* d_in, const int* in_sizes, int n_in,
                              void* d_out, int out_size, void* d_ws, size_t ws_size,
                              hipStream_t stream) {
  const float* x   = (const float*)d_in[0];
  const int*   ei  = (const int*)d_in[1];
  const float* ea  = (const float*)d_in[2];
  const float* Wm1 = (const float*)d_in[3];
  const float* bm1 = (const float*)d_in[4];
  const float* Wm2 = (const float*)d_in[5];
  const float* bm2 = (const float*)d_in[6];
  const float* Wu1 = (const float*)d_in[7];
  const float* bu1 = (const float*)d_in[8];
  const float* Wu2 = (const float*)d_in[9];
  const float* bu2 = (const float*)d_in[10];
  const float* Wh1 = (const float*)d_in[11];
  const float* bh1 = (const float*)d_in[12];
  const float* Wh2 = (const float*)d_in[13];
  const float* bh2 = (const float*)d_in[14];
  float* out = (float*)d_out;
  const int N = in_sizes[0] / 9;
  const int E = in_sizes[2];

  char* wsb = (char*)d_ws;
  size_t pos = 0;
  auto alloc = [&](size_t b) {
    pos = (pos + 255) & ~(size_t)255;
    char* p = wsb + pos;
    pos += b;
    return (void*)p;
  };
  int*   cnt   = (int*)alloc((size_t)N * 4);        // histogram
  int*   offs  = (int*)alloc((size_t)(N + 1) * 4);  // CSR offsets
  int4*  sedge = (int4*)alloc((size_t)E * 16);      // (src,dst,ea,0), dst-sorted
  float* P0    = (float*)alloc((size_t)N * 32 * 4);
  float* P1    = (float*)alloc((size_t)N * 32 * 4);
  float* G     = (float*)alloc((size_t)N * 32 * 4); // per-node aggregate
  float* hA    = (float*)alloc((size_t)N * 9 * 4);
  float* hB    = (float*)alloc((size_t)N * 9 * 4);
  int*   rank  = (int*)P1;  // alias: rank[E] dead before P1's first write

  hipMemsetAsync(cnt, 0, (size_t)N * 4, stream);

  premsg_kernel<<<(N + 255) / 256, 256, 0, stream>>>(x, Wm1, bm1, P0, N);
  rank_kernel<<<(E + 255) / 256, 256, 0, stream>>>(ei, cnt, rank, E);
  scan_kernel<<<1, 1024, 0, stream>>>(cnt, offs, N);
  place_kernel<<<(E + 255) / 256, 256, 0, stream>>>(ei, ea, offs, rank, sedge, E);

  int ab = (E + 255) / 256;
  int ub = (N + 255) / 256;
  // round 0
  hipMemsetAsync(G, 0, (size_t)N * 32 * 4, stream);
  agg_kernel<<<ab, 256, 0, stream>>>(sedge, P0, G, Wm1, Wm2, bm2, E);
  update_kernel<0><<<ub, 256, 0, stream>>>(G, x, hA, P1,
      Wm1, bm1, Wu1, bu1, Wu2, bu2, Wh1, bh1, Wh2, bh2, nullptr, N);
  // round 1
  hipMemsetAsync(G, 0, (size_t)N * 32 * 4, stream);
  agg_kernel<<<ab, 256, 0, stream>>>(sedge, P1, G, Wm1, Wm2, bm2, E);
  update_kernel<0><<<ub, 256, 0, stream>>>(G, hA, hB, P0,
      Wm1, bm1, Wu1, bu1, Wu2, bu2, Wh1, bh1, Wh2, bh2, nullptr, N);
  // round 2 + head
  hipMemsetAsync(G, 0, (size_t)N * 32 * 4, stream);
  agg_kernel<<<ab, 256, 0, stream>>>(sedge, P0, G, Wm1, Wm2, bm2, E);
  update_kernel<1><<<ub, 256, 0, stream>>>(G, hB, nullptr, nullptr,
      Wm1, bm1, Wu1, bu1, Wu2, bu2, Wh1, bh1, Wh2, bh2, out, N);
}

// Round 7
// 758.419 us; speedup vs baseline: 1.5735x; 1.0018x over previous
//
#include <hip/hip_runtime.h>
#include <math.h>

// ---------------- CSR build (2 edge passes: rank+count, then place) ----------------

__global__ void rank_kernel(const int* __restrict__ ei, int* __restrict__ cnt,
                            int* __restrict__ rank, int E) {
  int e = blockIdx.x * blockDim.x + threadIdx.x;
  if (e < E) rank[e] = atomicAdd(&cnt[ei[E + e]], 1);
}

__global__ __launch_bounds__(1024) void scan_kernel(int* __restrict__ cnt,
                                                    int* __restrict__ offs, int N) {
  __shared__ int part[1024];
  int tid = threadIdx.x;
  int chunk = (N + 1023) >> 10;
  int s = tid * chunk;
  int epos = s + chunk; if (epos > N) epos = N;
  int sum = 0;
  for (int i = s; i < epos; ++i) sum += cnt[i];
  part[tid] = sum;
  __syncthreads();
  for (int off = 1; off < 1024; off <<= 1) {
    int v = (tid >= off) ? part[tid - off] : 0;
    __syncthreads();
    part[tid] += v;
    __syncthreads();
  }
  int base = part[tid] - sum;  // exclusive prefix of this thread's chunk
  for (int i = s; i < epos; ++i) {
    offs[i] = base;
    base += cnt[i];
  }
  if (tid == 1023) offs[N] = part[1023];
}

// sedge[i] = (src, dst, edge_attr bits, 0), sorted by dst
__global__ void place_kernel(const int* __restrict__ ei, const float* __restrict__ ea,
                             const int* __restrict__ offs, const int* __restrict__ rank,
                             int4* __restrict__ sedge, int E) {
  int e = blockIdx.x * blockDim.x + threadIdx.x;
  if (e >= E) return;
  int d = ei[E + e];
  sedge[offs[d] + rank[e]] = make_int4(ei[e], d, __float_as_int(ea[e]), 0);
}

// ---------------- P = h @ Wm1[:9] + bm1 (round 0 only; later rounds fused) -------

__global__ __launch_bounds__(256) void premsg_kernel(const float* __restrict__ h,
    const float* __restrict__ Wm1, const float* __restrict__ bm1,
    float* __restrict__ P, int N) {
  int n = blockIdx.x * blockDim.x + threadIdx.x;
  if (n >= N) return;
  float hv[9];
  #pragma unroll
  for (int i = 0; i < 9; ++i) hv[i] = h[(size_t)n * 9 + i];
  float acc[32];
  #pragma unroll
  for (int k = 0; k < 32; ++k) acc[k] = bm1[k];
  #pragma unroll
  for (int i = 0; i < 9; ++i)
    #pragma unroll
    for (int k = 0; k < 32; ++k) acc[k] = fmaf(hv[i], Wm1[i * 32 + k], acc[k]);
  float4* Pv = (float4*)(P + (size_t)n * 32);
  #pragma unroll
  for (int jv = 0; jv < 8; ++jv)
    Pv[jv] = make_float4(acc[jv * 4], acc[jv * 4 + 1], acc[jv * 4 + 2], acc[jv * 4 + 3]);
}

// ---------------- edge-parallel message + segmented-scan aggregate ----------------
// One lane per edge (perfect balance). Live set ~60 floats; launch_bounds(256,4)
// caps the allocator at 128 VGPR so it lands ~64-100 with NO scratch/AGPR churn
// (round-4 counters: VGPR=32 + 74 MB spill writebacks = the 4x VALU inflation).
// dst-sorted edges: segmented Hillis-Steele scan per 64-lane window, run-end
// lanes atomicAdd to G (~2.4M atomics/round vs 51M naive).

__global__ __launch_bounds__(256, 4) void agg_kernel(
    const int4* __restrict__ sedge, const float* __restrict__ Pin,
    float* __restrict__ G, const float* __restrict__ Wm1,
    const float* __restrict__ Wm2, const float* __restrict__ bm2, int E) {
  int e = blockIdx.x * blockDim.x + threadIdx.x;
  int lane = threadIdx.x & 63;
  bool valid = e < E;
  int4 se = valid ? sedge[e] : make_int4(0, -1, 0, 0);
  int dst = se.y;
  float eav = __int_as_float(se.z);
  const float* __restrict__ Wm1t = Wm1 + 288;  // row 9 (edge_attr row)

  float p[32];
  const float4* Pv = (const float4*)(Pin + (size_t)se.x * 32);
  #pragma unroll
  for (int jv = 0; jv < 8; ++jv) {
    float4 v = Pv[jv];
    p[jv*4+0] = v.x; p[jv*4+1] = v.y; p[jv*4+2] = v.z; p[jv*4+3] = v.w;
  }
  // layer-1 tail in place: p becomes h1 = relu(P[src] + ea * Wm1[row 9])
  #pragma unroll
  for (int j = 0; j < 32; ++j) p[j] = fmaxf(fmaf(eav, Wm1t[j], p[j]), 0.f);

  // hoisted segment masks (dst is loop-invariant): mask[s]=1 iff dst[lane-2^s]==dst
  float segm[6];
  #pragma unroll
  for (int s = 0; s < 6; ++s) {
    int sh = 1 << s;
    int pd = __shfl_up(dst, sh);
    segm[s] = (lane >= sh && pd == dst) ? 1.f : 0.f;
  }
  int nextdst = __shfl_down(dst, 1);
  bool is_end = valid && ((lane == 63) || (nextdst != dst));

  // layer-2 in 4 chunks of 8 channels; scan+atomic per chunk keeps live set small
  #pragma unroll
  for (int c = 0; c < 4; ++c) {
    float t[8];
    #pragma unroll
    for (int k = 0; k < 8; ++k) t[k] = bm2[c * 8 + k];
    #pragma unroll
    for (int j = 0; j < 32; ++j) {
      float hj = p[j];
      #pragma unroll
      for (int k = 0; k < 8; ++k) t[k] = fmaf(hj, Wm2[j * 32 + c * 8 + k], t[k]);
    }
    #pragma unroll
    for (int k = 0; k < 8; ++k) t[k] = fmaxf(t[k], 0.f);
    // segmented inclusive scan (exact for sorted keys; pad lanes are dst=-1)
    #pragma unroll
    for (int s = 0; s < 6; ++s) {
      int sh = 1 << s;
      #pragma unroll
      for (int k = 0; k < 8; ++k) {
        float u = __shfl_up(t[k], sh);
        t[k] = fmaf(segm[s], u, t[k]);
      }
    }
    if (is_end) {
      float* g = G + (size_t)dst * 32 + c * 8;
      #pragma unroll
      for (int k = 0; k < 8; ++k) atomicAdd(&g[k], t[k]);
    }
  }
}

// ---------------- node update (+ premsg for next round, or h2o head) -------------

template <int MODE>  // 0: write hout + Pout ; 1: final round, write sigmoid head
__global__ __launch_bounds__(256) void update_kernel(
    const float* __restrict__ G, const float* __restrict__ hin,
    float* __restrict__ hout, float* __restrict__ Pout,
    const float* __restrict__ Wm1, const float* __restrict__ bm1,
    const float* __restrict__ Wu1, const float* __restrict__ bu1,
    const float* __restrict__ Wu2, const float* __restrict__ bu2,
    const float* __restrict__ Wh1, const float* __restrict__ bh1,
    const float* __restrict__ Wh2, const float* __restrict__ bh2,
    float* __restrict__ out, int N) {
  int n = blockIdx.x * blockDim.x + threadIdx.x;
  if (n >= N) return;
  float aggr[32];
  const float4* Gv = (const float4*)(G + (size_t)n * 32);
  #pragma unroll
  for (int jv = 0; jv < 8; ++jv) {
    float4 v = Gv[jv];
    aggr[jv*4+0] = v.x; aggr[jv*4+1] = v.y; aggr[jv*4+2] = v.z; aggr[jv*4+3] = v.w;
  }
  float hv[9];
  #pragma unroll
  for (int i = 0; i < 9; ++i) hv[i] = hin[(size_t)n * 9 + i];
  float u1[16];
  #pragma unroll
  for (int q = 0; q < 16; ++q) {
    float a = bu1[q];
    #pragma unroll
    for (int i = 0; i < 9; ++i) a = fmaf(hv[i], Wu1[i * 16 + q], a);
    #pragma unroll
    for (int k = 0; k < 32; ++k) a = fmaf(aggr[k], Wu1[(9 + k) * 16 + q], a);
    u1[q] = fmaxf(a, 0.f);
  }
  float emb[8];
  #pragma unroll
  for (int r = 0; r < 8; ++r) {
    float a = bu2[r];
    #pragma unroll
    for (int q = 0; q < 16; ++q) a = fmaf(u1[q], Wu2[q * 8 + r], a);
    emb[r] = fmaxf(a, 0.f);
  }
  if constexpr (MODE == 0) {
    // fused premessage for next round: P' = h' @ Wm1[:9] + bm1, h' = [state, emb]
    float acc[32];
    #pragma unroll
    for (int k = 0; k < 32; ++k) acc[k] = fmaf(hv[0], Wm1[k], bm1[k]);
    #pragma unroll
    for (int r = 0; r < 8; ++r)
      #pragma unroll
      for (int k = 0; k < 32; ++k) acc[k] = fmaf(emb[r], Wm1[(1 + r) * 32 + k], acc[k]);
    hout[(size_t)n * 9] = hv[0];
    #pragma unroll
    for (int r = 0; r < 8; ++r) hout[(size_t)n * 9 + 1 + r] = emb[r];
    float4* Pv = (float4*)(Pout + (size_t)n * 32);
    #pragma unroll
    for (int jv = 0; jv < 8; ++jv)
      Pv[jv] = make_float4(acc[jv*4], acc[jv*4+1], acc[jv*4+2], acc[jv*4+3]);
  } else {
    // h2o head: out = sigmoid(relu(emb @ Wh1 + bh1) @ Wh2 + bh2)
    float o[16];
    #pragma unroll
    for (int q = 0; q < 16; ++q) {
      float a = bh1[q];
      #pragma unroll
      for (int r = 0; r < 8; ++r) a = fmaf(emb[r], Wh1[r * 16 + q], a);
      o[q] = fmaxf(a, 0.f);
    }
    float z = bh2[0];
    #pragma unroll
    for (int q = 0; q < 16; ++q) z = fmaf(o[q], Wh2[q], z);
    out[n] = 1.f / (1.f + expf(-z));
  }
}

// ---------------- launch ----------------

extern "C" void kernel_launch(void* const* d_in, const int* in_sizes, int n_in,
                              void* d_out, int out_size, void* d_ws, size_t ws_size,
                              hipStream_t stream) {
  const float* x   = (const float*)d_in[0];
  const int*   ei  = (const int*)d_in[1];
  const float* ea  = (const float*)d_in[2];
  const float* Wm1 = (const float*)d_in[3];
  const float* bm1 = (const float*)d_in[4];
  const float* Wm2 = (const float*)d_in[5];
  const float* bm2 = (const float*)d_in[6];
  const float* Wu1 = (const float*)d_in[7];
  const float* bu1 = (const float*)d_in[8];
  const float* Wu2 = (const float*)d_in[9];
  const float* bu2 = (const float*)d_in[10];
  const float* Wh1 = (const float*)d_in[11];
  const float* bh1 = (const float*)d_in[12];
  const float* Wh2 = (const float*)d_in[13];
  const float* bh2 = (const float*)d_in[14];
  float* out = (float*)d_out;
  const int N = in_sizes[0] / 9;
  const int E = in_sizes[2];

  char* wsb = (char*)d_ws;
  size_t pos = 0;
  auto alloc = [&](size_t b) {
    pos = (pos + 255) & ~(size_t)255;
    char* p = wsb + pos;
    pos += b;
    return (void*)p;
  };
  int*   cnt   = (int*)alloc((size_t)N * 4);        // histogram
  int*   offs  = (int*)alloc((size_t)(N + 1) * 4);  // CSR offsets
  int4*  sedge = (int4*)alloc((size_t)E * 16);      // (src,dst,ea,0), dst-sorted
  float* P0    = (float*)alloc((size_t)N * 32 * 4);
  float* P1    = (float*)alloc((size_t)N * 32 * 4);
  float* G     = (float*)alloc((size_t)N * 32 * 4); // per-node aggregate
  float* hA    = (float*)alloc((size_t)N * 9 * 4);
  float* hB    = (float*)alloc((size_t)N * 9 * 4);
  int*   rank  = (int*)P1;  // alias: rank[E] dead before P1's first write

  hipMemsetAsync(cnt, 0, (size_t)N * 4, stream);

  premsg_kernel<<<(N + 255) / 256, 256, 0, stream>>>(x, Wm1, bm1, P0, N);
  rank_kernel<<<(E + 255) / 256, 256, 0, stream>>>(ei, cnt, rank, E);
  scan_kernel<<<1, 1024, 0, stream>>>(cnt, offs, N);
  place_kernel<<<(E + 255) / 256, 256, 0, stream>>>(ei, ea, offs, rank, sedge, E);

  int ab = (E + 255) / 256;
  int ub = (N + 255) / 256;
  // round 0
  hipMemsetAsync(G, 0, (size_t)N * 32 * 4, stream);
  agg_kernel<<<ab, 256, 0, stream>>>(sedge, P0, G, Wm1, Wm2, bm2, E);
  update_kernel<0><<<ub, 256, 0, stream>>>(G, x, hA, P1,
      Wm1, bm1, Wu1, bu1, Wu2, bu2, Wh1, bh1, Wh2, bh2, nullptr, N);
  // round 1
  hipMemsetAsync(G, 0, (size_t)N * 32 * 4, stream);
  agg_kernel<<<ab, 256, 0, stream>>>(sedge, P1, G, Wm1, Wm2, bm2, E);
  update_kernel<0><<<ub, 256, 0, stream>>>(G, hA, hB, P0,
      Wm1, bm1, Wu1, bu1, Wu2, bu2, Wh1, bh1, Wh2, bh2, nullptr, N);
  // round 2 + head
  hipMemsetAsync(G, 0, (size_t)N * 32 * 4, stream);
  agg_kernel<<<ab, 256, 0, stream>>>(sedge, P0, G, Wm1, Wm2, bm2, E);
  update_kernel<1><<<ub, 256, 0, stream>>>(G, hB, nullptr, nullptr,
      Wm1, bm1, Wu1, bu1, Wu2, bu2, Wh1, bh1, Wh2, bh2, out, N);
}

// Round 8
// 756.701 us; speedup vs baseline: 1.5770x; 1.0023x over previous
//
#include <hip/hip_runtime.h>
#include <math.h>

typedef float f8 __attribute__((ext_vector_type(8)));

__device__ __forceinline__ f8 fma8(float a, f8 b, f8 c) {
  f8 r;
  #pragma unroll
  for (int i = 0; i < 8; ++i) r[i] = fmaf(a, b[i], c[i]);
  return r;
}
__device__ __forceinline__ f8 relu8(f8 v) {
  f8 r;
  #pragma unroll
  for (int i = 0; i < 8; ++i) r[i] = fmaxf(v[i], 0.f);
  return r;
}

// ---------------- CSR build (2 edge passes: rank+count, then place) ----------------

__global__ void rank_kernel(const int* __restrict__ ei, int* __restrict__ cnt,
                            int* __restrict__ rank, int E) {
  int e = blockIdx.x * blockDim.x + threadIdx.x;
  if (e < E) rank[e] = atomicAdd(&cnt[ei[E + e]], 1);
}

__global__ __launch_bounds__(1024) void scan_kernel(int* __restrict__ cnt,
                                                    int* __restrict__ offs, int N) {
  __shared__ int part[1024];
  int tid = threadIdx.x;
  int chunk = (N + 1023) >> 10;
  int s = tid * chunk;
  int epos = s + chunk; if (epos > N) epos = N;
  int sum = 0;
  for (int i = s; i < epos; ++i) sum += cnt[i];
  part[tid] = sum;
  __syncthreads();
  for (int off = 1; off < 1024; off <<= 1) {
    int v = (tid >= off) ? part[tid - off] : 0;
    __syncthreads();
    part[tid] += v;
    __syncthreads();
  }
  int base = part[tid] - sum;  // exclusive prefix of this thread's chunk
  for (int i = s; i < epos; ++i) {
    offs[i] = base;
    base += cnt[i];
  }
  if (tid == 1023) offs[N] = part[1023];
}

// sedge[i] = (src, dst, edge_attr bits, 0), sorted by dst
__global__ void place_kernel(const int* __restrict__ ei, const float* __restrict__ ea,
                             const int* __restrict__ offs, const int* __restrict__ rank,
                             int4* __restrict__ sedge, int E) {
  int e = blockIdx.x * blockDim.x + threadIdx.x;
  if (e >= E) return;
  int d = ei[E + e];
  sedge[offs[d] + rank[e]] = make_int4(ei[e], d, __float_as_int(ea[e]), 0);
}

// ---------------- P = h @ Wm1[:9] + bm1 (round 0 only; later rounds fused) -------

__global__ __launch_bounds__(256) void premsg_kernel(const float* __restrict__ h,
    const float* __restrict__ Wm1, const float* __restrict__ bm1,
    float* __restrict__ P, int N) {
  int n = blockIdx.x * blockDim.x + threadIdx.x;
  if (n >= N) return;
  float hv[9];
  #pragma unroll
  for (int i = 0; i < 9; ++i) hv[i] = h[(size_t)n * 9 + i];
  float acc[32];
  #pragma unroll
  for (int k = 0; k < 32; ++k) acc[k] = bm1[k];
  #pragma unroll
  for (int i = 0; i < 9; ++i)
    #pragma unroll
    for (int k = 0; k < 32; ++k) acc[k] = fmaf(hv[i], Wm1[i * 32 + k], acc[k]);
  float4* Pv = (float4*)(P + (size_t)n * 32);
  #pragma unroll
  for (int jv = 0; jv < 8; ++jv)
    Pv[jv] = make_float4(acc[jv * 4], acc[jv * 4 + 1], acc[jv * 4 + 2], acc[jv * 4 + 3]);
}

// ---------------- edge-parallel message + segmented-scan aggregate ----------------
// One lane per edge. All hot state in ext_vector_type(8) SSA values with
// compile-time indices ONLY (rounds 4-7: C arrays stayed allocas -> scratch:
// VGPR=32, 74 MB spill writebacks, VALUBusy 34%). dst-sorted edges: segmented
// Hillis-Steele scan per 64-lane window, run-end lanes atomicAdd to G.

__global__ __launch_bounds__(256, 2) void agg_kernel(
    const int4* __restrict__ sedge, const float* __restrict__ Pin,
    float* __restrict__ G, const float* __restrict__ Wm1,
    const float* __restrict__ Wm2, const float* __restrict__ bm2, int E) {
  int e = blockIdx.x * blockDim.x + threadIdx.x;
  int lane = threadIdx.x & 63;
  bool valid = e < E;
  int4 se = valid ? sedge[e] : make_int4(0, -1, 0, 0);
  int dst = se.y;
  float eav = __int_as_float(se.z);

  // gather P row (4 x 32B) and apply layer-1 tail: h1 = relu(P[src] + ea*Wm1row9)
  const f8* __restrict__ Pv  = (const f8*)(Pin + (size_t)se.x * 32);
  const f8* __restrict__ W1t = (const f8*)(Wm1 + 288);  // row 9 (edge_attr row)
  f8 p[4];
  #pragma unroll
  for (int q = 0; q < 4; ++q) p[q] = Pv[q];
  #pragma unroll
  for (int q = 0; q < 4; ++q) p[q] = relu8(fma8(eav, W1t[q], p[q]));

  // hoisted segment masks (dst loop-invariant): segm[s]=1 iff dst[lane-2^s]==dst
  float segm[6];
  #pragma unroll
  for (int s = 0; s < 6; ++s) {
    int sh = 1 << s;
    int pd = __shfl_up(dst, sh);
    segm[s] = (lane >= sh && pd == dst) ? 1.f : 0.f;
  }
  int nextdst = __shfl_down(dst, 1);
  bool is_end = valid && ((lane == 63) || (nextdst != dst));

  const f8* __restrict__ W2 = (const f8*)Wm2;   // row j, chunk c at [j*4 + c]
  const f8* __restrict__ B2 = (const f8*)bm2;

  // layer-2 in 4 chunks of 8 output channels (weights wave-uniform -> s_loads)
  #pragma unroll
  for (int c = 0; c < 4; ++c) {
    f8 t = B2[c];
    #pragma unroll
    for (int j = 0; j < 32; ++j)
      t = fma8(p[j >> 3][j & 7], W2[j * 4 + c], t);
    t = relu8(t);
    // segmented inclusive scan (exact for sorted keys; pad lanes are dst=-1)
    #pragma unroll
    for (int s = 0; s < 6; ++s) {
      f8 u;
      #pragma unroll
      for (int k = 0; k < 8; ++k) u[k] = __shfl_up(t[k], 1 << s);
      t = fma8(segm[s], u, t);
    }
    if (is_end) {
      float* g = G + (size_t)dst * 32 + c * 8;
      #pragma unroll
      for (int k = 0; k < 8; ++k) atomicAdd(&g[k], t[k]);
    }
  }
}

// ---------------- node update (+ premsg for next round, or h2o head) -------------

template <int MODE>  // 0: write hout + Pout ; 1: final round, write sigmoid head
__global__ __launch_bounds__(256) void update_kernel(
    const float* __restrict__ G, const float* __restrict__ hin,
    float* __restrict__ hout, float* __restrict__ Pout,
    const float* __restrict__ Wm1, const float* __restrict__ bm1,
    const float* __restrict__ Wu1, const float* __restrict__ bu1,
    const float* __restrict__ Wu2, const float* __restrict__ bu2,
    const float* __restrict__ Wh1, const float* __restrict__ bh1,
    const float* __restrict__ Wh2, const float* __restrict__ bh2,
    float* __restrict__ out, int N) {
  int n = blockIdx.x * blockDim.x + threadIdx.x;
  if (n >= N) return;
  float aggr[32];
  const float4* Gv = (const float4*)(G + (size_t)n * 32);
  #pragma unroll
  for (int jv = 0; jv < 8; ++jv) {
    float4 v = Gv[jv];
    aggr[jv*4+0] = v.x; aggr[jv*4+1] = v.y; aggr[jv*4+2] = v.z; aggr[jv*4+3] = v.w;
  }
  float hv[9];
  #pragma unroll
  for (int i = 0; i < 9; ++i) hv[i] = hin[(size_t)n * 9 + i];
  float u1[16];
  #pragma unroll
  for (int q = 0; q < 16; ++q) {
    float a = bu1[q];
    #pragma unroll
    for (int i = 0; i < 9; ++i) a = fmaf(hv[i], Wu1[i * 16 + q], a);
    #pragma unroll
    for (int k = 0; k < 32; ++k) a = fmaf(aggr[k], Wu1[(9 + k) * 16 + q], a);
    u1[q] = fmaxf(a, 0.f);
  }
  float emb[8];
  #pragma unroll
  for (int r = 0; r < 8; ++r) {
    float a = bu2[r];
    #pragma unroll
    for (int q = 0; q < 16; ++q) a = fmaf(u1[q], Wu2[q * 8 + r], a);
    emb[r] = fmaxf(a, 0.f);
  }
  if constexpr (MODE == 0) {
    // fused premessage for next round: P' = h' @ Wm1[:9] + bm1, h' = [state, emb]
    float acc[32];
    #pragma unroll
    for (int k = 0; k < 32; ++k) acc[k] = fmaf(hv[0], Wm1[k], bm1[k]);
    #pragma unroll
    for (int r = 0; r < 8; ++r)
      #pragma unroll
      for (int k = 0; k < 32; ++k) acc[k] = fmaf(emb[r], Wm1[(1 + r) * 32 + k], acc[k]);
    hout[(size_t)n * 9] = hv[0];
    #pragma unroll
    for (int r = 0; r < 8; ++r) hout[(size_t)n * 9 + 1 + r] = emb[r];
    float4* Pv = (float4*)(Pout + (size_t)n * 32);
    #pragma unroll
    for (int jv = 0; jv < 8; ++jv)
      Pv[jv] = make_float4(acc[jv*4], acc[jv*4+1], acc[jv*4+2], acc[jv*4+3]);
  } else {
    // h2o head: out = sigmoid(relu(emb @ Wh1 + bh1) @ Wh2 + bh2)
    float o[16];
    #pragma unroll
    for (int q = 0; q < 16; ++q) {
      float a = bh1[q];
      #pragma unroll
      for (int r = 0; r < 8; ++r) a = fmaf(emb[r], Wh1[r * 16 + q], a);
      o[q] = fmaxf(a, 0.f);
    }
    float z = bh2[0];
    #pragma unroll
    for (int q = 0; q < 16; ++q) z = fmaf(o[q], Wh2[q], z);
    out[n] = 1.f / (1.f + expf(-z));
  }
}

// ---------------- launch ----------------

extern "C" void kernel_launch(void* const* d_in, const int* in_sizes, int n_in,
                              void* d_out, int out_size, void* d_ws, size_t ws_size,
                              hipStream_t stream) {
  const float* x   = (const float*)d_in[0];
  const int*   ei  = (const int*)d_in[1];
  const float* ea  = (const float*)d_in[2];
  const float* Wm1 = (const float*)d_in[3];
  const float* bm1 = (const float*)d_in[4];
  const float* Wm2 = (const float*)d_in[5];
  const float* bm2 = (const float*)d_in[6];
  const float* Wu1 = (const float*)d_in[7];
  const float* bu1 = (const float*)d_in[8];
  const float* Wu2 = (const float*)d_in[9];
  const float* bu2 = (const float*)d_in[10];
  const float* Wh1 = (const float*)d_in[11];
  const float* bh1 = (const float*)d_in[12];
  const float* Wh2 = (const float*)d_in[13];
  const float* bh2 = (const float*)d_in[14];
  float* out = (float*)d_out;
  const int N = in_sizes[0] / 9;
  const int E = in_sizes[2];

  char* wsb = (char*)d_ws;
  size_t pos = 0;
  auto alloc = [&](size_t b) {
    pos = (pos + 255) & ~(size_t)255;
    char* p = wsb + pos;
    pos += b;
    return (void*)p;
  };
  int*   cnt   = (int*)alloc((size_t)N * 4);        // histogram
  int*   offs  = (int*)alloc((size_t)(N + 1) * 4);  // CSR offsets
  int4*  sedge = (int4*)alloc((size_t)E * 16);      // (src,dst,ea,0), dst-sorted
  float* P0    = (float*)alloc((size_t)N * 32 * 4);
  float* P1    = (float*)alloc((size_t)N * 32 * 4);
  float* G     = (float*)alloc((size_t)N * 32 * 4); // per-node aggregate
  float* hA    = (float*)alloc((size_t)N * 9 * 4);
  float* hB    = (float*)alloc((size_t)N * 9 * 4);
  int*   rank  = (int*)P1;  // alias: rank[E] dead before P1's first write

  hipMemsetAsync(cnt, 0, (size_t)N * 4, stream);

  premsg_kernel<<<(N + 255) / 256, 256, 0, stream>>>(x, Wm1, bm1, P0, N);
  rank_kernel<<<(E + 255) / 256, 256, 0, stream>>>(ei, cnt, rank, E);
  scan_kernel<<<1, 1024, 0, stream>>>(cnt, offs, N);
  place_kernel<<<(E + 255) / 256, 256, 0, stream>>>(ei, ea, offs, rank, sedge, E);

  int ab = (E + 255) / 256;
  int ub = (N + 255) / 256;
  // round 0
  hipMemsetAsync(G, 0, (size_t)N * 32 * 4, stream);
  agg_kernel<<<ab, 256, 0, stream>>>(sedge, P0, G, Wm1, Wm2, bm2, E);
  update_kernel<0><<<ub, 256, 0, stream>>>(G, x, hA, P1,
      Wm1, bm1, Wu1, bu1, Wu2, bu2, Wh1, bh1, Wh2, bh2, nullptr, N);
  // round 1
  hipMemsetAsync(G, 0, (size_t)N * 32 * 4, stream);
  agg_kernel<<<ab, 256, 0, stream>>>(sedge, P1, G, Wm1, Wm2, bm2, E);
  update_kernel<0><<<ub, 256, 0, stream>>>(G, hA, hB, P0,
      Wm1, bm1, Wu1, bu1, Wu2, bu2, Wh1, bh1, Wh2, bh2, nullptr, N);
  // round 2 + head
  hipMemsetAsync(G, 0, (size_t)N * 32 * 4, stream);
  agg_kernel<<<ab, 256, 0, stream>>>(sedge, P0, G, Wm1, Wm2, bm2, E);
  update_kernel<1><<<ub, 256, 0, stream>>>(G, hB, nullptr, nullptr,
      Wm1, bm1, Wu1, bu1, Wu2, bu2, Wh1, bh1, Wh2, bh2, out, N);
}